// Round 2
// 3322.401 us; speedup vs baseline: 1.4250x; 1.4250x over previous
//
#include <hip/hip_runtime.h>
#include <stdint.h>

// GNNCell: 2x SAGEConv(lstm) + 2 MLP heads. N=100000, D=16, H=128, fp32 I/O.
// R7 passed (absmax 3.9e-3) at 4734 us; lstm_comb = 78% (2x1850us), latency-
// bound on X gathers: 32 tiny requests/lane/step (8B hi + 4B lo per gate at
// 256B stride) and the MFMA chain seeded from X (gather on critical path).
// R8: (1) gate-interleaved X layout [node][j*4+g] -> per-lane 48B contiguous
//     (2x16B hi + 1x16B lo), 12 requests/lane/step, quad-groups form 128B
//     runs; (2) MFMA from zero acc, X added post-chain (gather latency hidden
//     under 48 MFMAs + activations); (3) nbr staged to LDS [64][17] once
//     (broadcast reads, address off the vm queue). xgemm grid swapped so the
//     8 col-blocks of a row-block are adjacent (L2 write-merge of the
//     interleaved stores).
// R9: identical resubmit of R8 — round 1 bench was an infra failure
//     ("container failed twice"), no kernel verdict. Source re-audited:
//     bounds, barriers, LDS indices all safe.
// Precision scheme unchanged: X fp16-hi + i8-lo(2^-15), split-bf16 3-MFMA
// recurrence/X-GEMM/combine, hs bf16 hi/lo planes.

typedef __attribute__((ext_vector_type(8))) short short8_t;
typedef __attribute__((ext_vector_type(4))) float float4_t;
typedef __attribute__((ext_vector_type(4))) unsigned uint4_t;
typedef _Float16 half8_t __attribute__((ext_vector_type(8)));
typedef _Float16 half4_t __attribute__((ext_vector_type(4)));

#define NNODES 100000
#define DNB 16
#define LOSCALE 32768.0f
#define LOINV   3.0517578125e-5f   // 2^-15

__device__ __forceinline__ float fsigf(float x) {
    return __builtin_amdgcn_rcpf(1.f + __expf(-x));
}
__device__ __forceinline__ float ftanhf(float x) {
    return 1.f - 2.f * __builtin_amdgcn_rcpf(1.f + __expf(2.f * x));
}
__device__ __forceinline__ unsigned f2b(float f) {  // RNE f32->bf16 (finite)
    unsigned u = __float_as_uint(f);
    return (u + 0x7FFFu + ((u >> 16) & 1u)) >> 16;
}
__device__ __forceinline__ float blo(unsigned u) { return __uint_as_float(u << 16); }
__device__ __forceinline__ float bhi(unsigned u) { return __uint_as_float(u & 0xFFFF0000u); }
// split fp32[8] -> bf16 hi + bf16 lo fragments (compensated GEMM inputs)
__device__ __forceinline__ void splitf8(const float* __restrict__ p, short8_t& hi, short8_t& lo) {
    float4_t a = *(const float4_t*)p;
    float4_t b = *(const float4_t*)(p + 4);
#pragma unroll
    for (int j = 0; j < 8; ++j) {
        float x = j < 4 ? a[j] : b[j - 4];
        unsigned hb = f2b(x);
        float hf = __uint_as_float(hb << 16);
        unsigned lb = f2b(x - hf);
        hi[j] = (short)hb;
        lo[j] = (short)lb;
    }
}
// fp32[8] -> bf16x8 (plain cast, head path)
__device__ __forceinline__ short8_t cvtb8(const float* __restrict__ p) {
    float4_t a = *(const float4_t*)p;
    float4_t b = *(const float4_t*)(p + 4);
    short8_t r;
    r[0] = (short)f2b(a[0]); r[1] = (short)f2b(a[1]);
    r[2] = (short)f2b(a[2]); r[3] = (short)f2b(a[3]);
    r[4] = (short)f2b(b[0]); r[5] = (short)f2b(b[1]);
    r[6] = (short)f2b(b[2]); r[7] = (short)f2b(b[3]);
    return r;
}

// ---------------------------------------------------------------------------
// X = h @ Wih.T + b, split-bf16 3-MFMA (rel ~2^-16), stored fp16-hi + i8-lo.
// Output layout is GATE-INTERLEAVED: element c = g*128+j stored at
// node*512 + j*4 + g, so the lstm gather reads one contiguous 48B run/lane.
// Grid = (8 col-blocks, 1563 row-blocks): col-blocks of one row-block are
// dispatch-adjacent -> L2 merges the interleaved partial-line stores.
// ---------------------------------------------------------------------------
__global__ __launch_bounds__(256) void xgemm_split(
    const float* __restrict__ A, const float* __restrict__ B,
    const float* __restrict__ bias, _Float16* __restrict__ Chi,
    char* __restrict__ Clo)
{
    const int tid  = threadIdx.x;
    const int wave = tid >> 6, lane = tid & 63;
    const int l15  = lane & 15, quad = lane >> 4;
    const int r0   = blockIdx.y * 64 + wave * 16;
    const int c0   = blockIdx.x * 64;

    int arow = r0 + l15;
    if (arow >= NNODES) arow = NNODES - 1;

    float4_t acc[4];
#pragma unroll
    for (int ct = 0; ct < 4; ++ct) acc[ct] = (float4_t){0.f, 0.f, 0.f, 0.f};

#pragma unroll
    for (int kc = 0; kc < 4; ++kc) {
        const int kk = kc * 32 + quad * 8;
        short8_t ah, al;
        splitf8(A + (size_t)arow * 128 + kk, ah, al);
#pragma unroll
        for (int ct = 0; ct < 4; ++ct) {
            short8_t bh, bl;
            splitf8(B + (size_t)(c0 + ct * 16 + l15) * 128 + kk, bh, bl);
            acc[ct] = __builtin_amdgcn_mfma_f32_16x16x32_bf16(ah, bh, acc[ct], 0, 0, 0);
            acc[ct] = __builtin_amdgcn_mfma_f32_16x16x32_bf16(ah, bl, acc[ct], 0, 0, 0);
            acc[ct] = __builtin_amdgcn_mfma_f32_16x16x32_bf16(al, bh, acc[ct], 0, 0, 0);
        }
    }

#pragma unroll
    for (int ct = 0; ct < 4; ++ct) {
        int c = c0 + ct * 16 + l15;
        float bb = bias[c];
        const int jj = c & 127, gg = c >> 7;          // gate-interleaved slot
#pragma unroll
        for (int r = 0; r < 4; ++r) {
            int rowo = r0 + quad * 4 + r;
            if (rowo < NNODES) {
                float v = acc[ct][r] + bb;
                _Float16 hi = (_Float16)v;
                float res = v - (float)hi;
                int q = (int)rintf(res * LOSCALE);
                q = q > 127 ? 127 : (q < -127 ? -127 : q);
                Chi[(size_t)rowo * 512 + jj * 4 + gg] = hi;
                Clo[(size_t)rowo * 512 + jj * 4 + gg] = (char)q;
            }
        }
    }
}

// ---------------------------------------------------------------------------
// Fused 16-step LSTM + combine. Block = 64 nodes, 512 threads (8 waves).
// Wave w owns hidden slice j in [16w, 16w+16) for ALL 4 gates (4 tiles).
// Gates transposed D[gaterow][node]: i/f/g/o of one (node,j) share a lane.
// hs in DOUBLE-BUFFERED bf16 hi/lo LDS planes -> ONE barrier per step.
// X gathers: 3 contiguous 16B loads/lane/nt (gate-interleaved layout),
// issued at step start; consumed AFTER the MFMA chain (ac from zero).
// nbr staged in LDS [64][17] (conflict-free broadcast reads).
// Epilogue: h'=relu(hin@Ws.T+hn@Wn.T+bs+bn); 8 waves = 4 node-grps x 2
// ct-halves; barrier between hin loads and in-place stores.
// ---------------------------------------------------------------------------
__global__ __launch_bounds__(512, 2) void lstm_comb(
    const _Float16* __restrict__ Xhi, const char* __restrict__ Xlo,
    const int* __restrict__ nbr, const float* __restrict__ Whh,
    const float* hin, const float* __restrict__ Ws,
    const float* __restrict__ Wn, const float* __restrict__ bs,
    const float* __restrict__ bn, float* hout)
{
    __shared__ short hsAhi[64 * 136], hsAlo[64 * 136];
    __shared__ short hsBhi[64 * 136], hsBlo[64 * 136];
    __shared__ int   nbrs[64 * 17];

    const int tid  = threadIdx.x;
    const int wave = tid >> 6, lane = tid & 63;
    const int l15  = lane & 15, quad = lane >> 4;
    const int n0   = blockIdx.x * 64;
    const int jb   = wave * 16;
    const int xoff = jb * 4 + quad * 16;   // gate-interleaved lane offset

    for (int i = tid; i < 64 * 136 / 2; i += 512) {
        ((unsigned*)hsAhi)[i] = 0;
        ((unsigned*)hsAlo)[i] = 0;
    }
    for (int i = tid; i < 64 * DNB; i += 512) {
        int node = n0 + (i >> 4);
        if (node >= NNODES) node = NNODES - 1;
        nbrs[(i >> 4) * 17 + (i & 15)] = nbr[node * DNB + (i & 15)];
    }

    // Whh split fragments: 4 gates x 4 k-chunks x (hi,lo) = 32 frags = 128 VGPR
    short8_t whi[4][4], wlo[4][4];
#pragma unroll
    for (int g = 0; g < 4; ++g)
#pragma unroll
        for (int kc = 0; kc < 4; ++kc)
            splitf8(Whh + (size_t)(g * 128 + jb + l15) * 128 + kc * 32 + quad * 8,
                    whi[g][kc], wlo[g][kc]);

    float cs[4][4], nh[4][4];
#pragma unroll
    for (int a = 0; a < 4; ++a)
#pragma unroll
        for (int b = 0; b < 4; ++b) { cs[a][b] = 0.f; nh[a][b] = 0.f; }

    __syncthreads();

// hi value (g,r) lives at vector slot r*4+g; lo byte g of word r.
#define XV(nt, r, g)                                                                \
    ((float)(((r) * 4 + (g)) < 8 ? xh0[nt][(r) * 4 + (g)] : xh1[nt][(r) * 4 + (g) - 8]) \
     + (float)((signed char)(xl4[nt][(r)] >> ((g) * 8))) * LOINV)

#define LSTM_STEP(rdHi, rdLo, wrHi, wrLo, T)                                        \
    {                                                                               \
        half8_t xh0[4], xh1[4]; uint4_t xl4[4];                                     \
        _Pragma("unroll")                                                           \
        for (int nt = 0; nt < 4; ++nt) {                                            \
            int gi = nbrs[(nt * 16 + l15) * 17 + (T)];                              \
            size_t xb = (size_t)gi * 512 + xoff;                                    \
            xh0[nt] = *(const half8_t*)(Xhi + xb);                                  \
            xh1[nt] = *(const half8_t*)(Xhi + xb + 8);                              \
            xl4[nt] = *(const uint4_t*)(Xlo + xb);                                  \
        }                                                                           \
        _Pragma("unroll")                                                           \
        for (int nt = 0; nt < 4; ++nt) {                                            \
            short8_t hfh[4], hfl[4];                                                \
            _Pragma("unroll")                                                       \
            for (int kc = 0; kc < 4; ++kc) {                                        \
                hfh[kc] = *(const short8_t*)&(rdHi)[(nt * 16 + l15) * 136 + kc * 32 + quad * 8]; \
                hfl[kc] = *(const short8_t*)&(rdLo)[(nt * 16 + l15) * 136 + kc * 32 + quad * 8]; \
            }                                                                       \
            float4_t ac[4];                                                         \
            _Pragma("unroll")                                                       \
            for (int g = 0; g < 4; ++g) {                                           \
                float4_t a = (float4_t){0.f, 0.f, 0.f, 0.f};                        \
                _Pragma("unroll")                                                   \
                for (int kc = 0; kc < 4; ++kc) {                                    \
                    a = __builtin_amdgcn_mfma_f32_16x16x32_bf16(whi[g][kc], hfh[kc], a, 0, 0, 0); \
                    a = __builtin_amdgcn_mfma_f32_16x16x32_bf16(whi[g][kc], hfl[kc], a, 0, 0, 0); \
                    a = __builtin_amdgcn_mfma_f32_16x16x32_bf16(wlo[g][kc], hfh[kc], a, 0, 0, 0); \
                }                                                                   \
                ac[g] = a;                                                          \
            }                                                                       \
            _Pragma("unroll")                                                       \
            for (int r = 0; r < 4; ++r) {                                           \
                float iv = ac[0][r] + XV(nt, r, 0);                                 \
                float fv = ac[1][r] + XV(nt, r, 1);                                 \
                float gv = ac[2][r] + XV(nt, r, 2);                                 \
                float ov = ac[3][r] + XV(nt, r, 3);                                 \
                float c = fsigf(fv) * cs[nt][r] + fsigf(iv) * ftanhf(gv);           \
                cs[nt][r] = c;                                                      \
                nh[nt][r] = fsigf(ov) * ftanhf(c);                                  \
            }                                                                       \
        }                                                                           \
        _Pragma("unroll")                                                           \
        for (int nt = 0; nt < 4; ++nt) {                                            \
            unsigned hb[4], lb[4];                                                  \
            _Pragma("unroll")                                                       \
            for (int r = 0; r < 4; ++r) {                                           \
                float v = nh[nt][r];                                                \
                hb[r] = f2b(v);                                                     \
                lb[r] = f2b(v - __uint_as_float(hb[r] << 16));                      \
            }                                                                       \
            uint2 ph, pl;                                                           \
            ph.x = hb[0] | (hb[1] << 16); ph.y = hb[2] | (hb[3] << 16);             \
            pl.x = lb[0] | (lb[1] << 16); pl.y = lb[2] | (lb[3] << 16);             \
            const int o = (nt * 16 + l15) * 136 + jb + quad * 4;                    \
            *(uint2*)&(wrHi)[o] = ph;                                               \
            *(uint2*)&(wrLo)[o] = pl;                                               \
        }                                                                           \
        __syncthreads();                                                            \
    }

    for (int tp = 0; tp < 8; ++tp) {
        LSTM_STEP(hsAhi, hsAlo, hsBhi, hsBlo, 2 * tp);      // even t: read A write B
        LSTM_STEP(hsBhi, hsBlo, hsAhi, hsAlo, 2 * tp + 1);  // odd  t: read B write A
    }
#undef LSTM_STEP
#undef XV
    // t=15 (odd) wrote A planes -> h_neigh lives in hsA.

    // ---- fused combine: h' = relu(hin@Ws.T + hn@Wn.T + bs + bn) ----
    // wave -> node group (wave&3, 16 nodes) x ct half (wave>>2, 4 tiles).
    const int ng = wave & 3, ch = wave >> 2;
    const int nodeA = n0 + ng * 16 + l15;
    const int nclA  = nodeA < NNODES ? nodeA : NNODES - 1;
    short8_t ahh[4], ahl[4], anh[4], anl[4];
#pragma unroll
    for (int kc = 0; kc < 4; ++kc) {
        splitf8(hin + (size_t)nclA * 128 + kc * 32 + quad * 8, ahh[kc], ahl[kc]);
        anh[kc] = *(const short8_t*)&hsAhi[(ng * 16 + l15) * 136 + kc * 32 + quad * 8];
        anl[kc] = *(const short8_t*)&hsAlo[(ng * 16 + l15) * 136 + kc * 32 + quad * 8];
    }
    __syncthreads();   // all hin reads done before any in-place store

#pragma unroll
    for (int ct = 0; ct < 4; ++ct) {
        const int ctg = ch * 4 + ct;
        float4_t acc = (float4_t){0.f, 0.f, 0.f, 0.f};
#pragma unroll
        for (int kc = 0; kc < 4; ++kc) {
            const int kk = kc * 32 + quad * 8;
            short8_t bh, bl;
            splitf8(Ws + (size_t)(ctg * 16 + l15) * 128 + kk, bh, bl);
            acc = __builtin_amdgcn_mfma_f32_16x16x32_bf16(ahh[kc], bh, acc, 0, 0, 0);
            acc = __builtin_amdgcn_mfma_f32_16x16x32_bf16(ahh[kc], bl, acc, 0, 0, 0);
            acc = __builtin_amdgcn_mfma_f32_16x16x32_bf16(ahl[kc], bh, acc, 0, 0, 0);
            splitf8(Wn + (size_t)(ctg * 16 + l15) * 128 + kk, bh, bl);
            acc = __builtin_amdgcn_mfma_f32_16x16x32_bf16(anh[kc], bh, acc, 0, 0, 0);
            acc = __builtin_amdgcn_mfma_f32_16x16x32_bf16(anh[kc], bl, acc, 0, 0, 0);
            acc = __builtin_amdgcn_mfma_f32_16x16x32_bf16(anl[kc], bh, acc, 0, 0, 0);
        }
        const int c = ctg * 16 + l15;
        const float bb = bs[c] + bn[c];
#pragma unroll
        for (int r = 0; r < 4; ++r) {
            int rowo = n0 + ng * 16 + quad * 4 + r;
            if (rowo < NNODES) {
                float v = acc[r] + bb;
                hout[(size_t)rowo * 128 + c] = v > 0.f ? v : 0.f;
            }
        }
    }
}

// ---------------------------------------------------------------------------
// Stacked head layer: rows [0,N) use (Bc,bc), rows [N,2N) use (Bn,bn).
// afmt=1: A fp32 N rows (both halves read same rows); afmt=0: A bf16 2N rows.
// ---------------------------------------------------------------------------
__global__ __launch_bounds__(256) void headgemm_b(
    const float* __restrict__ A32, const short* __restrict__ A16,
    const float* __restrict__ Bc, const float* __restrict__ Bn,
    const float* __restrict__ bc, const float* __restrict__ bn,
    short* __restrict__ C, int afmt)
{
    const int tid  = threadIdx.x;
    const int wave = tid >> 6, lane = tid & 63;
    const int l15  = lane & 15, quad = lane >> 4;
    const int r0   = blockIdx.x * 64 + wave * 16;
    const int c0   = blockIdx.y * 64;

    const float* Bw = (r0 < NNODES) ? Bc : Bn;
    const float* bw = (r0 < NNODES) ? bc : bn;
    int arow = r0 + l15;
    if (afmt && arow >= NNODES) arow -= NNODES;

    float4_t acc[4];
#pragma unroll
    for (int ct = 0; ct < 4; ++ct) acc[ct] = (float4_t){0.f, 0.f, 0.f, 0.f};

#pragma unroll
    for (int kc = 0; kc < 4; ++kc) {
        const int kk = kc * 32 + quad * 8;
        short8_t af = afmt ? cvtb8(A32 + (size_t)arow * 128 + kk)
                           : *(const short8_t*)(A16 + (size_t)arow * 128 + kk);
#pragma unroll
        for (int ct = 0; ct < 4; ++ct) {
            short8_t bf = cvtb8(Bw + (size_t)(c0 + ct * 16 + l15) * 128 + kk);
            acc[ct] = __builtin_amdgcn_mfma_f32_16x16x32_bf16(af, bf, acc[ct], 0, 0, 0);
        }
    }

#pragma unroll
    for (int ct = 0; ct < 4; ++ct) {
        int c = c0 + ct * 16 + l15;
        float bb = bw[c];
#pragma unroll
        for (int r = 0; r < 4; ++r) {
            int rowo = r0 + quad * 4 + r;
            float v = acc[ct][r] + bb;
            if (v < 0.f) v = 0.f;
            C[(size_t)rowo * 128 + c] = (short)f2b(v);
        }
    }
}

// out[n*C+c] = x[n,:].W[c,:] + b[c]   (C = 10 or 1), bf16 acts, fp32 out.
__global__ __launch_bounds__(256) void final_b(
    const short* __restrict__ xin, const float* __restrict__ W,
    const float* __restrict__ b, float* __restrict__ out, int C)
{
    int idx = blockIdx.x * blockDim.x + threadIdx.x;
    if (idx >= NNODES * C) return;
    int n = idx / C, c = idx - n * C;
    const short* xr = xin + (size_t)n * 128;
    const float* wr = W + (size_t)c * 128;
    float acc = b[c];
#pragma unroll
    for (int i = 0; i < 16; ++i) {
        uint4 xv = *(const uint4*)(xr + i * 8);
        const float* w = wr + i * 8;
        acc += blo(xv.x) * w[0] + bhi(xv.x) * w[1]
             + blo(xv.y) * w[2] + bhi(xv.y) * w[3]
             + blo(xv.z) * w[4] + bhi(xv.z) * w[5]
             + blo(xv.w) * w[6] + bhi(xv.w) * w[7];
    }
    out[idx] = acc;
}

// ===========================================================================
extern "C" void kernel_launch(void* const* d_in, const int* in_sizes, int n_in,
                              void* d_out, int out_size, void* d_ws, size_t ws_size,
                              hipStream_t stream)
{
    const float* h0     = (const float*)d_in[0];
    const int*   nbr    = (const int*)d_in[1];
    const float* Wih    = (const float*)d_in[2];   // [2,512,128]
    const float* Whh    = (const float*)d_in[3];   // [2,512,128]
    const float* lb     = (const float*)d_in[4];   // [2,512]
    const float* Wself  = (const float*)d_in[5];   // [2,128,128]
    const float* bself  = (const float*)d_in[6];
    const float* Wneigh = (const float*)d_in[7];
    const float* bneigh = (const float*)d_in[8];
    const float* clsW   = (const float*)d_in[9];   // [5,128,128]
    const float* clsb   = (const float*)d_in[10];
    const float* clsoW  = (const float*)d_in[11];  // [10,128]
    const float* clsob  = (const float*)d_in[12];
    const float* cnfW   = (const float*)d_in[13];
    const float* cnfb   = (const float*)d_in[14];
    const float* cnfoW  = (const float*)d_in[15];  // [1,128]
    const float* cnfob  = (const float*)d_in[16];

    char* ws = (char*)d_ws;
    _Float16* Xhi = (_Float16*)ws;                 // [0, 102.4M)
    char*     Xlo = ws + 102400000;                // [102.4M, 153.6M)
    short*    actA = (short*)ws;                   // phase B: [0, 51.2M)
    short*    actB = (short*)(ws + 51200000);      // phase B: [51.2M, 102.4M)

    float* out = (float*)d_out;
    float* oC  = out;                   // [N,10]
    float* hO  = out + 1000000;         // [N,128] output 1; h1/h2 live here
    float* oL  = out + 13800000;        // [N,1]

    dim3 gx(8, 1563);    // xgemm: cols fast (L2 write-merge), M=100000, NC=512
    dim3 gl(1563);       // lstm_comb, 512 thr
    dim3 gh(3125, 2);    // heads: M=200000, NC=128, 256 thr

    // ---- layer 1: h1 -> d_out h slot ----
    xgemm_split<<<gx, dim3(256), 0, stream>>>(h0, Wih, lb, Xhi, Xlo);
    lstm_comb<<<gl, dim3(512), 0, stream>>>(Xhi, Xlo, nbr, Whh, h0,
                                            Wself, Wneigh, bself, bneigh, hO);
    // ---- layer 2: h2 -> same slot, in-place ----
    xgemm_split<<<gx, dim3(256), 0, stream>>>(hO, Wih + 65536, lb + 512, Xhi, Xlo);
    lstm_comb<<<gl, dim3(512), 0, stream>>>(Xhi, Xlo, nbr, Whh + 65536, hO,
                                            Wself + 16384, Wneigh + 16384,
                                            bself + 128, bneigh + 128, hO);

    // ---- heads: stacked cls (rows<N) / cnf (rows>=N) ----
    headgemm_b<<<gh, dim3(256), 0, stream>>>(hO, nullptr, clsW, cnfW, clsb, cnfb, actA, 1);
    short* cur = actA; short* nxt = actB;
    for (int i = 1; i < 5; ++i) {
        headgemm_b<<<gh, dim3(256), 0, stream>>>(nullptr, cur, clsW + i * 16384, cnfW + i * 16384,
                                                 clsb + i * 128, cnfb + i * 128, nxt, 0);
        short* tv = cur; cur = nxt; nxt = tv;
    }
    final_b<<<dim3((NNODES * 10 + 255) / 256), dim3(256), 0, stream>>>(cur, clsoW, clsob, oC, 10);
    final_b<<<dim3((NNODES + 255) / 256), dim3(256), 0, stream>>>(cur + (size_t)NNODES * 128,
                                                                  cnfoW, cnfob, oL, 1);
}